// Round 2
// baseline (1675.448 us; speedup 1.0000x reference)
//
#include <hip/hip_runtime.h>
#include <math.h>

// ---------------------------------------------------------------------------
// CNE: 2-layer GCN (PyG GCNConv norm w/ self loops) + outcome/propensity heads
// N=100000, E=1600000, IN=128, H=64, T=C=20000. All fp32.
//
// R1: replace random-scatter CSR build (107MB HBM writes from 16x line
// amplification) with block-segmented bucket binning (bucket = dst>>7),
// and aggregate per-bucket into a 129x64 LDS fp32 accumulator (ds_add_f32).
// ---------------------------------------------------------------------------

#define CHUNK 16384  // edges per binning block
#define BSH 7        // bucket shift: 128 dst nodes per bucket

__device__ __forceinline__ float wave_sum64(float v) {
#pragma unroll
  for (int m = 32; m >= 1; m >>= 1) v += __shfl_xor(v, m, 64);
  return v;
}

__device__ __forceinline__ float lrelu(float x) { return x > 0.0f ? x : 0.01f * x; }

// ---- fused: per-node degree atomics + per-bucket LDS hist + blkcount ----
__global__ void k_count(const int* __restrict__ dst, int E, int nbuck,
                        int* __restrict__ count, int* __restrict__ bcount,
                        int* __restrict__ blkcount) {
  __shared__ int bh[1024];
  int t = threadIdx.x;
  for (int i = t; i < nbuck; i += 256) bh[i] = 0;
  __syncthreads();
  int e0 = blockIdx.x * CHUNK;
  int e1 = min(e0 + CHUNK, E);
  for (int e = e0 + t; e < e1; e += 256) {
    int d = dst[e];
    atomicAdd(&count[d], 1);
    atomicAdd(&bh[d >> BSH], 1);
  }
  __syncthreads();
  for (int i = t; i < nbuck; i += 256) {
    int c = bh[i];
    blkcount[blockIdx.x * nbuck + i] = c;
    if (c) atomicAdd(&bcount[i], c);
  }
}

// ---- dinv = (indeg+1)^-1/2 ----
__global__ void k_dinv(const int* __restrict__ count, float* __restrict__ dinv, int N) {
  int i = blockIdx.x * blockDim.x + threadIdx.x;
  if (i < N) dinv[i] = 1.0f / sqrtf((float)(count[i] + 1));
}

// ---- exclusive scan of bucket counts (nbuck <= 1024), one block ----
__global__ void k_scan1(const int* __restrict__ bcount, int* __restrict__ bbase, int nbuck) {
  __shared__ int s[1024];
  int t = threadIdx.x;
  int v = (t < nbuck) ? bcount[t] : 0;
  s[t] = v;
  __syncthreads();
  for (int off = 1; off < 1024; off <<= 1) {
    int u = (t >= off) ? s[t - off] : 0;
    __syncthreads();
    s[t] += u;
    __syncthreads();
  }
  if (t < nbuck) bbase[t] = s[t] - v;
}

// ---- per-(block,bucket) offsets: column scan over nblk entries ----
__global__ void k_scan2(const int* __restrict__ blkcount, const int* __restrict__ bbase,
                        int* __restrict__ blkoff, int nblk, int nbuck) {
  int lane = threadIdx.x & 63;
  int b = (blockIdx.x * blockDim.x + threadIdx.x) >> 6;  // one wave per bucket
  if (b >= nbuck) return;
  int carry = bbase[b];
  for (int base = 0; base < nblk; base += 64) {
    int i = base + lane;
    int v = (i < nblk) ? blkcount[i * nbuck + b] : 0;
    int x = v;
#pragma unroll
    for (int off = 1; off < 64; off <<= 1) {
      int u = __shfl_up(x, off, 64);
      if (lane >= off) x += u;
    }
    if (i < nblk) blkoff[i * nbuck + b] = carry + (x - v);
    carry += __shfl(x, 63, 64);
  }
}

// ---- binned scatter: block-contiguous segments per bucket ----
// pack: src (bits 0..19) | (dst & 127) << 20
__global__ void k_bscatter(const int* __restrict__ src, const int* __restrict__ dst,
                           int E, int nbuck, const int* __restrict__ blkoff,
                           unsigned int* __restrict__ pairs) {
  __shared__ int cur[1024];
  int t = threadIdx.x;
  for (int i = t; i < nbuck; i += 256) cur[i] = blkoff[blockIdx.x * nbuck + i];
  __syncthreads();
  int e0 = blockIdx.x * CHUNK;
  int e1 = min(e0 + CHUNK, E);
  for (int e = e0 + t; e < e1; e += 256) {
    int s = src[e];
    int d = dst[e];
    int p = atomicAdd(&cur[d >> BSH], 1);
    pairs[p] = (unsigned int)s | ((unsigned int)(d & 127) << 20);
  }
}

// ---- G = dinv * (X @ W)   X:[N,K] W:[K,64] ----
template <int K>
__launch_bounds__(256)
__global__ void k_gemm_scale(const float* __restrict__ X, const float* __restrict__ W,
                             const float* __restrict__ dinv, float* __restrict__ G, int N) {
  int lane = threadIdx.x & 63;
  float w[K];
#pragma unroll
  for (int k = 0; k < K; k++) w[k] = W[k * 64 + lane];
  int wid = (blockIdx.x * blockDim.x + threadIdx.x) >> 6;
  int nwave = (gridDim.x * blockDim.x) >> 6;
  for (int row = wid; row < N; row += nwave) {
    int r = __builtin_amdgcn_readfirstlane(row);
    const float4* xr = (const float4*)(X + (size_t)r * K);
    float a0 = 0.f, a1 = 0.f, a2 = 0.f, a3 = 0.f;
#pragma unroll
    for (int k = 0; k < K / 4; k++) {
      float4 xv = xr[k];
      a0 = fmaf(xv.x, w[4 * k + 0], a0);
      a1 = fmaf(xv.y, w[4 * k + 1], a1);
      a2 = fmaf(xv.z, w[4 * k + 2], a2);
      a3 = fmaf(xv.w, w[4 * k + 3], a3);
    }
    G[(size_t)r * 64 + lane] = (a0 + a1 + a2 + a3) * dinv[r];
  }
}

// ---- aggregation: one block per bucket, LDS fp32 accumulator ----
// Out[i] = act(bias + dinv[i]*(G[i] + sum_{src in in(i)} G[src]))
__launch_bounds__(256)
__global__ void k_agg_lds(const float* __restrict__ G, const unsigned int* __restrict__ pairs,
                          const int* __restrict__ bbase, const int* __restrict__ bcount,
                          const float* __restrict__ dinv, const float* __restrict__ bias,
                          float* __restrict__ Out, int N, int do_relu) {
  __shared__ float acc[129 * 64];  // row 128 = dump row for tail lanes
  int t = threadIdx.x, lane = t & 63, w = t >> 6;
  int b = blockIdx.x;
  for (int i = t; i < 129 * 64; i += 256) acc[i] = 0.f;
  __syncthreads();
  int start = bbase[b], cnt = bcount[b];
  for (int base = w * 64; base < cnt; base += 256) {
    int idx = base + lane;
    unsigned int pv = (idx < cnt) ? pairs[start + idx] : (128u << 20);
#pragma unroll
    for (int j = 0; j < 64; j += 8) {
      float v[8];
      int rr[8];
#pragma unroll
      for (int u = 0; u < 8; u++) {
        unsigned int pj = __shfl(pv, j + u, 64);
        rr[u] = (int)(pj >> 20);
        v[u] = G[(size_t)(pj & 0xFFFFFu) * 64 + lane];
      }
#pragma unroll
      for (int u = 0; u < 8; u++) atomicAdd(&acc[rr[u] * 64 + lane], v[u]);
    }
  }
  __syncthreads();
  int nd0 = b << BSH;
  for (int r = w; r < 128; r += 4) {
    int i = nd0 + r;
    if (i < N) {
      float val = bias[lane] + dinv[i] * (G[(size_t)i * 64 + lane] + acc[r * 64 + lane]);
      if (do_relu) val = fmaxf(val, 0.f);
      Out[(size_t)i * 64 + lane] = val;
    }
  }
}

// ---- outcome heads ----
__global__ void k_heads(const float* __restrict__ Z, const int* __restrict__ treat,
                        const int* __restrict__ ctrl, int T, int C,
                        const float* __restrict__ Wy1, const float* __restrict__ by1,
                        const float* __restrict__ Wy0, const float* __restrict__ by0,
                        float* __restrict__ y1, float* __restrict__ yc0,
                        float* __restrict__ y0, float* __restrict__ yc1) {
  int lane = threadIdx.x & 63;
  int wid = (blockIdx.x * blockDim.x + threadIdx.x) >> 6;
  if (wid >= T + C) return;
  bool treated = wid < T;
  int idx = treated ? wid : wid - T;
  int row = treated ? treat[idx] : ctrl[idx];
  row = __builtin_amdgcn_readfirstlane(row);
  float v = Z[(size_t)row * 64 + lane];
  float s1 = wave_sum64(v * Wy1[lane]);
  float s0 = wave_sum64(v * Wy0[lane]);
  if (lane == 0) {
    float a1 = lrelu(s1 + by1[0]);
    float a0 = lrelu(s0 + by0[0]);
    if (treated) { y1[idx] = a1; yc0[idx] = a0; }
    else         { yc1[idx] = a1; y0[idx] = a0; }
  }
}

// ---- propensity head ----
__launch_bounds__(256)
__global__ void k_tprob(const float* __restrict__ Z, const float* __restrict__ Wp1,
                        const float* __restrict__ bp1, const float* __restrict__ Wp2,
                        const float* __restrict__ bp2, float* __restrict__ tprob, int N) {
  int lane = threadIdx.x & 63;
  float w[64];
#pragma unroll
  for (int k = 0; k < 64; k++) w[k] = Wp1[k * 64 + lane];
  float wp2a = Wp2[lane * 2 + 0], wp2b = Wp2[lane * 2 + 1];
  float b1l = bp1[lane];
  float b20 = bp2[0], b21 = bp2[1];
  int wid = (blockIdx.x * blockDim.x + threadIdx.x) >> 6;
  int nwave = (gridDim.x * blockDim.x) >> 6;
  for (int row = wid; row < N; row += nwave) {
    int r = __builtin_amdgcn_readfirstlane(row);
    const float4* zr = (const float4*)(Z + (size_t)r * 64);
    float a0 = 0.f, a1 = 0.f, a2 = 0.f, a3 = 0.f;
#pragma unroll
    for (int k = 0; k < 16; k++) {
      float4 xv = zr[k];
      a0 = fmaf(xv.x, w[4 * k + 0], a0);
      a1 = fmaf(xv.y, w[4 * k + 1], a1);
      a2 = fmaf(xv.z, w[4 * k + 2], a2);
      a3 = fmaf(xv.w, w[4 * k + 3], a3);
    }
    float hp = lrelu(b1l + a0 + a1 + a2 + a3);
    float s0 = wave_sum64(hp * wp2a);
    float s1 = wave_sum64(hp * wp2b);
    if (lane == 0) {
      tprob[(size_t)r * 2 + 0] = lrelu(s0 + b20);
      tprob[(size_t)r * 2 + 1] = lrelu(s1 + b21);
    }
  }
}

extern "C" void kernel_launch(void* const* d_in, const int* in_sizes, int n_in,
                              void* d_out, int out_size, void* d_ws, size_t ws_size,
                              hipStream_t stream) {
  const int IN = 128, H = 64;
  const int N = in_sizes[0] / IN;
  const int E = in_sizes[1] / 2;
  const int T = in_sizes[2];
  const int C = in_sizes[3];
  const int nbuck = (N + 127) >> BSH;            // 782 for N=100000
  const int nblk = (E + CHUNK - 1) / CHUNK;      // 98 for E=1.6M

  const float* x    = (const float*)d_in[0];
  const int*   ei   = (const int*)d_in[1];
  const int*   src  = ei;
  const int*   dst  = ei + E;
  const int*   trt  = (const int*)d_in[2];
  const int*   ctl  = (const int*)d_in[3];
  const float* W1   = (const float*)d_in[4];
  const float* b1   = (const float*)d_in[5];
  const float* W2   = (const float*)d_in[6];
  const float* b2   = (const float*)d_in[7];
  const float* Wy1  = (const float*)d_in[8];
  const float* by1  = (const float*)d_in[9];
  const float* Wy0  = (const float*)d_in[10];
  const float* by0  = (const float*)d_in[11];
  const float* Wp1  = (const float*)d_in[12];
  const float* bp1  = (const float*)d_in[13];
  const float* Wp2  = (const float*)d_in[14];
  const float* bp2  = (const float*)d_in[15];

  float* out   = (float*)d_out;
  float* y1    = out;                          // [T]
  float* yc0   = out + T;                      // [T]
  float* y0    = out + 2 * T;                  // [C]
  float* yc1   = out + 2 * T + C;              // [C]
  float* tprob = out + 2 * T + 2 * C;          // [N,2]
  float* xZ2   = out + 2 * T + 2 * C + 2 * N;  // [N,64]

  // workspace layout (4-byte elems)
  int* count     = (int*)d_ws;                 // N   (zeroed)
  int* bcount    = count + N;                  // 1024 (zeroed)
  int* bbase     = bcount + 1024;              // 1024
  int* blkcount  = bbase + 1024;               // nblk*nbuck
  int* blkoff    = blkcount + (size_t)nblk * nbuck;  // nblk*nbuck
  unsigned int* pairs = (unsigned int*)(blkoff + (size_t)nblk * nbuck);  // E
  float* dinv    = (float*)(pairs + E);        // N
  float* g       = dinv + N;                   // N*H
  float* xZ1     = g + (size_t)N * H;          // N*H

  hipMemsetAsync(count, 0, sizeof(int) * ((size_t)N + 1024), stream);

  k_count<<<nblk, 256, 0, stream>>>(dst, E, nbuck, count, bcount, blkcount);
  k_dinv<<<(N + 255) / 256, 256, 0, stream>>>(count, dinv, N);
  k_scan1<<<1, 1024, 0, stream>>>(bcount, bbase, nbuck);
  k_scan2<<<(nbuck * 64 + 255) / 256, 256, 0, stream>>>(blkcount, bbase, blkoff, nblk, nbuck);
  k_bscatter<<<nblk, 256, 0, stream>>>(src, dst, E, nbuck, blkoff, pairs);

  // layer 1: g = dinv*(x@W1); xZ1 = relu(b1 + dinv*(g_self + sum g))
  k_gemm_scale<128><<<1024, 256, 0, stream>>>(x, W1, dinv, g, N);
  k_agg_lds<<<nbuck, 256, 0, stream>>>(g, pairs, bbase, bcount, dinv, b1, xZ1, N, 1);

  // layer 2: g = dinv*(xZ1@W2); xZ2 = b2 + dinv*(g_self + sum g)
  k_gemm_scale<64><<<1024, 256, 0, stream>>>(xZ1, W2, dinv, g, N);
  k_agg_lds<<<nbuck, 256, 0, stream>>>(g, pairs, bbase, bcount, dinv, b2, xZ2, N, 0);

  // heads
  k_heads<<<((size_t)(T + C) * 64 + 255) / 256, 256, 0, stream>>>(
      xZ2, trt, ctl, T, C, Wy1, by1, Wy0, by0, y1, yc0, y0, yc1);
  k_tprob<<<2048, 256, 0, stream>>>(xZ2, Wp1, bp1, Wp2, bp2, tprob, N);
}

// Round 3
// 320.110 us; speedup vs baseline: 5.2340x; 5.2340x over previous
//
#include <hip/hip_runtime.h>
#include <hip/hip_fp16.h>
#include <math.h>

// ---------------------------------------------------------------------------
// CNE: 2-layer GCN (PyG GCNConv norm w/ self loops) + outcome/propensity heads
// N=100000, E=1600000, IN=128, H=64, T=C=20000.
//
// R3: binned CSR build (bucket hist -> scan -> binned scatter -> in-bucket
// sort w/ LDS cursors; no N-wide global atomics, no write amplification)
// + wave-per-node aggregation (100k waves, latency hidden by occupancy)
// + G stored fp16 to halve gather traffic (fp32 accumulate).
// ---------------------------------------------------------------------------

#define CHUNK 16384  // edges per binning block
#define BSH 7        // 128 dst nodes per bucket

__device__ __forceinline__ float wave_sum64(float v) {
#pragma unroll
  for (int m = 32; m >= 1; m >>= 1) v += __shfl_xor(v, m, 64);
  return v;
}

__device__ __forceinline__ float lrelu(float x) { return x > 0.0f ? x : 0.01f * x; }

// ---- bucket histogram per chunk (LDS only) ----
__global__ void k_count(const int* __restrict__ dst, int E, int nbuck,
                        int* __restrict__ bcount, int* __restrict__ blkcount) {
  __shared__ int bh[1024];
  int t = threadIdx.x;
  for (int i = t; i < nbuck; i += 256) bh[i] = 0;
  __syncthreads();
  int e0 = blockIdx.x * CHUNK;
  int e1 = min(e0 + CHUNK, E);
  for (int e = e0 + t; e < e1; e += 256) atomicAdd(&bh[dst[e] >> BSH], 1);
  __syncthreads();
  for (int i = t; i < nbuck; i += 256) {
    int c = bh[i];
    blkcount[blockIdx.x * nbuck + i] = c;
    if (c) atomicAdd(&bcount[i], c);
  }
}

// ---- exclusive scan of bucket counts (nbuck <= 1024), one block ----
__global__ void k_scan1(const int* __restrict__ bcount, int* __restrict__ bbase, int nbuck) {
  __shared__ int s[1024];
  int t = threadIdx.x;
  int v = (t < nbuck) ? bcount[t] : 0;
  s[t] = v;
  __syncthreads();
  for (int off = 1; off < 1024; off <<= 1) {
    int u = (t >= off) ? s[t - off] : 0;
    __syncthreads();
    s[t] += u;
    __syncthreads();
  }
  if (t < nbuck) bbase[t] = s[t] - v;
}

// ---- per-(block,bucket) offsets: column scan over nblk entries ----
__global__ void k_scan2(const int* __restrict__ blkcount, const int* __restrict__ bbase,
                        int* __restrict__ blkoff, int nblk, int nbuck) {
  int lane = threadIdx.x & 63;
  int b = (blockIdx.x * blockDim.x + threadIdx.x) >> 6;  // one wave per bucket
  if (b >= nbuck) return;
  int carry = bbase[b];
  for (int base = 0; base < nblk; base += 64) {
    int i = base + lane;
    int v = (i < nblk) ? blkcount[i * nbuck + b] : 0;
    int x = v;
#pragma unroll
    for (int off = 1; off < 64; off <<= 1) {
      int u = __shfl_up(x, off, 64);
      if (lane >= off) x += u;
    }
    if (i < nblk) blkoff[i * nbuck + b] = carry + (x - v);
    carry += __shfl(x, 63, 64);
  }
}

// ---- binned scatter: pack src (bits 0..19) | (dst & 127) << 20 ----
__global__ void k_bscatter(const int* __restrict__ src, const int* __restrict__ dst,
                           int E, int nbuck, const int* __restrict__ blkoff,
                           unsigned int* __restrict__ pairs) {
  __shared__ int cur[1024];
  int t = threadIdx.x;
  for (int i = t; i < nbuck; i += 256) cur[i] = blkoff[blockIdx.x * nbuck + i];
  __syncthreads();
  int e0 = blockIdx.x * CHUNK;
  int e1 = min(e0 + CHUNK, E);
  for (int e = e0 + t; e < e1; e += 256) {
    int s = src[e];
    int d = dst[e];
    int p = atomicAdd(&cur[d >> BSH], 1);
    pairs[p] = (unsigned int)s | ((unsigned int)(d & 127) << 20);
  }
}

// ---- in-bucket sort -> per-node CSR + degree + dinv ----
__global__ void k_sort(const unsigned int* __restrict__ pairs, const int* __restrict__ bbase,
                       const int* __restrict__ bcount, int* __restrict__ slot,
                       int* __restrict__ offs, int* __restrict__ cntout,
                       float* __restrict__ dinv, int N) {
  __shared__ int hist[128];
  __shared__ int loc[128];
  __shared__ int cur[128];
  int b = blockIdx.x, t = threadIdx.x;
  if (t < 128) hist[t] = 0;
  __syncthreads();
  int start = bbase[b], cnt = bcount[b];
  for (int i = t; i < cnt; i += 256) atomicAdd(&hist[pairs[start + i] >> 20], 1);
  __syncthreads();
  if (t < 128) loc[t] = hist[t];
  __syncthreads();
  for (int off = 1; off < 128; off <<= 1) {
    int u = (t >= off && t < 128) ? loc[t - off] : 0;
    __syncthreads();
    if (t < 128) loc[t] += u;
    __syncthreads();
  }
  if (t < 128) {
    int ex = loc[t] - hist[t];  // exclusive scan
    cur[t] = ex;
    int node = (b << BSH) + t;
    if (node < N) {
      offs[node] = start + ex;
      cntout[node] = hist[t];
      dinv[node] = rsqrtf((float)(hist[t] + 1));
    }
  }
  __syncthreads();
  for (int i = t; i < cnt; i += 256) {
    unsigned int p = pairs[start + i];
    int d = (int)(p >> 20);
    int pos = atomicAdd(&cur[d], 1);
    slot[start + pos] = (int)(p & 0xFFFFFu);
  }
}

// ---- G16 = fp16( dinv * (X @ W) )   X:[N,K] W:[K,64] ----
template <int K>
__launch_bounds__(256)
__global__ void k_gemm_scale(const float* __restrict__ X, const float* __restrict__ W,
                             const float* __restrict__ dinv, __half* __restrict__ G, int N) {
  int lane = threadIdx.x & 63;
  float w[K];
#pragma unroll
  for (int k = 0; k < K; k++) w[k] = W[k * 64 + lane];
  int wid = (blockIdx.x * blockDim.x + threadIdx.x) >> 6;
  int nwave = (gridDim.x * blockDim.x) >> 6;
  for (int row = wid; row < N; row += nwave) {
    int r = __builtin_amdgcn_readfirstlane(row);
    const float4* xr = (const float4*)(X + (size_t)r * K);
    float a0 = 0.f, a1 = 0.f, a2 = 0.f, a3 = 0.f;
#pragma unroll
    for (int k = 0; k < K / 4; k++) {
      float4 xv = xr[k];
      a0 = fmaf(xv.x, w[4 * k + 0], a0);
      a1 = fmaf(xv.y, w[4 * k + 1], a1);
      a2 = fmaf(xv.z, w[4 * k + 2], a2);
      a3 = fmaf(xv.w, w[4 * k + 3], a3);
    }
    G[(size_t)r * 64 + lane] = __float2half((a0 + a1 + a2 + a3) * dinv[r]);
  }
}

// ---- aggregation: wave per node; Out[i]=act(b + dinv[i]*(G[i]+sum G[src])) ----
__global__ void k_agg(const __half* __restrict__ G, const int* __restrict__ offs,
                      const int* __restrict__ count, const int* __restrict__ slot,
                      const float* __restrict__ dinv, const float* __restrict__ bias,
                      float* __restrict__ Out, int N, int do_relu) {
  int lane = threadIdx.x & 63;
  int wid = (blockIdx.x * blockDim.x + threadIdx.x) >> 6;
  if (wid >= N) return;
  int r = __builtin_amdgcn_readfirstlane(wid);
  int start = offs[r], cnt = count[r];
  float acc0 = __half2float(G[(size_t)r * 64 + lane]);
  float acc1 = 0.f, acc2 = 0.f, acc3 = 0.f;
  int j = 0;
  for (; j + 8 <= cnt; j += 8) {
    int s[8];
#pragma unroll
    for (int u = 0; u < 8; u++) s[u] = slot[start + j + u];
    float v[8];
#pragma unroll
    for (int u = 0; u < 8; u++) v[u] = __half2float(G[(size_t)s[u] * 64 + lane]);
    acc0 += v[0] + v[4];
    acc1 += v[1] + v[5];
    acc2 += v[2] + v[6];
    acc3 += v[3] + v[7];
  }
  for (; j < cnt; j++) {
    int s = slot[start + j];
    acc0 += __half2float(G[(size_t)s * 64 + lane]);
  }
  float val = bias[lane] + dinv[r] * (acc0 + acc1 + acc2 + acc3);
  if (do_relu) val = fmaxf(val, 0.f);
  Out[(size_t)r * 64 + lane] = val;
}

// ---- outcome heads ----
__global__ void k_heads(const float* __restrict__ Z, const int* __restrict__ treat,
                        const int* __restrict__ ctrl, int T, int C,
                        const float* __restrict__ Wy1, const float* __restrict__ by1,
                        const float* __restrict__ Wy0, const float* __restrict__ by0,
                        float* __restrict__ y1, float* __restrict__ yc0,
                        float* __restrict__ y0, float* __restrict__ yc1) {
  int lane = threadIdx.x & 63;
  int wid = (blockIdx.x * blockDim.x + threadIdx.x) >> 6;
  if (wid >= T + C) return;
  bool treated = wid < T;
  int idx = treated ? wid : wid - T;
  int row = treated ? treat[idx] : ctrl[idx];
  row = __builtin_amdgcn_readfirstlane(row);
  float v = Z[(size_t)row * 64 + lane];
  float s1 = wave_sum64(v * Wy1[lane]);
  float s0 = wave_sum64(v * Wy0[lane]);
  if (lane == 0) {
    float a1 = lrelu(s1 + by1[0]);
    float a0 = lrelu(s0 + by0[0]);
    if (treated) { y1[idx] = a1; yc0[idx] = a0; }
    else         { yc1[idx] = a1; y0[idx] = a0; }
  }
}

// ---- propensity head ----
__launch_bounds__(256)
__global__ void k_tprob(const float* __restrict__ Z, const float* __restrict__ Wp1,
                        const float* __restrict__ bp1, const float* __restrict__ Wp2,
                        const float* __restrict__ bp2, float* __restrict__ tprob, int N) {
  int lane = threadIdx.x & 63;
  float w[64];
#pragma unroll
  for (int k = 0; k < 64; k++) w[k] = Wp1[k * 64 + lane];
  float wp2a = Wp2[lane * 2 + 0], wp2b = Wp2[lane * 2 + 1];
  float b1l = bp1[lane];
  float b20 = bp2[0], b21 = bp2[1];
  int wid = (blockIdx.x * blockDim.x + threadIdx.x) >> 6;
  int nwave = (gridDim.x * blockDim.x) >> 6;
  for (int row = wid; row < N; row += nwave) {
    int r = __builtin_amdgcn_readfirstlane(row);
    const float4* zr = (const float4*)(Z + (size_t)r * 64);
    float a0 = 0.f, a1 = 0.f, a2 = 0.f, a3 = 0.f;
#pragma unroll
    for (int k = 0; k < 16; k++) {
      float4 xv = zr[k];
      a0 = fmaf(xv.x, w[4 * k + 0], a0);
      a1 = fmaf(xv.y, w[4 * k + 1], a1);
      a2 = fmaf(xv.z, w[4 * k + 2], a2);
      a3 = fmaf(xv.w, w[4 * k + 3], a3);
    }
    float hp = lrelu(b1l + a0 + a1 + a2 + a3);
    float s0 = wave_sum64(hp * wp2a);
    float s1 = wave_sum64(hp * wp2b);
    if (lane == 0) {
      tprob[(size_t)r * 2 + 0] = lrelu(s0 + b20);
      tprob[(size_t)r * 2 + 1] = lrelu(s1 + b21);
    }
  }
}

extern "C" void kernel_launch(void* const* d_in, const int* in_sizes, int n_in,
                              void* d_out, int out_size, void* d_ws, size_t ws_size,
                              hipStream_t stream) {
  const int IN = 128, H = 64;
  const int N = in_sizes[0] / IN;
  const int E = in_sizes[1] / 2;
  const int T = in_sizes[2];
  const int C = in_sizes[3];
  const int nbuck = (N + 127) >> BSH;         // 782
  const int nblk = (E + CHUNK - 1) / CHUNK;   // 98

  const float* x    = (const float*)d_in[0];
  const int*   ei   = (const int*)d_in[1];
  const int*   src  = ei;
  const int*   dst  = ei + E;
  const int*   trt  = (const int*)d_in[2];
  const int*   ctl  = (const int*)d_in[3];
  const float* W1   = (const float*)d_in[4];
  const float* b1   = (const float*)d_in[5];
  const float* W2   = (const float*)d_in[6];
  const float* b2   = (const float*)d_in[7];
  const float* Wy1  = (const float*)d_in[8];
  const float* by1  = (const float*)d_in[9];
  const float* Wy0  = (const float*)d_in[10];
  const float* by0  = (const float*)d_in[11];
  const float* Wp1  = (const float*)d_in[12];
  const float* bp1  = (const float*)d_in[13];
  const float* Wp2  = (const float*)d_in[14];
  const float* bp2  = (const float*)d_in[15];

  float* out   = (float*)d_out;
  float* y1    = out;                          // [T]
  float* yc0   = out + T;                      // [T]
  float* y0    = out + 2 * T;                  // [C]
  float* yc1   = out + 2 * T + C;              // [C]
  float* tprob = out + 2 * T + 2 * C;          // [N,2]
  float* xZ2   = out + 2 * T + 2 * C + 2 * N;  // [N,64]

  // workspace layout (4-byte units)
  int* bcount    = (int*)d_ws;                      // 1024 (zeroed)
  int* bbase     = bcount + 1024;                   // 1024
  int* blkcount  = bbase + 1024;                    // nblk*nbuck
  int* blkoff    = blkcount + (size_t)nblk * nbuck; // nblk*nbuck
  unsigned int* pairs = (unsigned int*)(blkoff + (size_t)nblk * nbuck);  // E
  int* slot      = (int*)(pairs + E);               // E
  int* offs      = slot + E;                        // N
  int* cnt       = offs + N;                        // N
  float* dinv    = (float*)(cnt + N);               // N
  __half* g16    = (__half*)(dinv + N);             // N*64 halves (N*32 words)
  float* xZ1     = (float*)(g16 + (size_t)N * 64);  // N*64

  hipMemsetAsync(bcount, 0, sizeof(int) * 1024, stream);

  k_count<<<nblk, 256, 0, stream>>>(dst, E, nbuck, bcount, blkcount);
  k_scan1<<<1, 1024, 0, stream>>>(bcount, bbase, nbuck);
  k_scan2<<<(nbuck * 64 + 255) / 256, 256, 0, stream>>>(blkcount, bbase, blkoff, nblk, nbuck);
  k_bscatter<<<nblk, 256, 0, stream>>>(src, dst, E, nbuck, blkoff, pairs);
  k_sort<<<nbuck, 256, 0, stream>>>(pairs, bbase, bcount, slot, offs, cnt, dinv, N);

  // layer 1
  k_gemm_scale<128><<<1024, 256, 0, stream>>>(x, W1, dinv, g16, N);
  k_agg<<<((size_t)N * 64 + 255) / 256, 256, 0, stream>>>(g16, offs, cnt, slot, dinv, b1, xZ1, N, 1);

  // layer 2
  k_gemm_scale<64><<<1024, 256, 0, stream>>>(xZ1, W2, dinv, g16, N);
  k_agg<<<((size_t)N * 64 + 255) / 256, 256, 0, stream>>>(g16, offs, cnt, slot, dinv, b2, xZ2, N, 0);

  // heads
  k_heads<<<((size_t)(T + C) * 64 + 255) / 256, 256, 0, stream>>>(
      xZ2, trt, ctl, T, C, Wy1, by1, Wy0, by0, y1, yc0, y0, yc1);
  k_tprob<<<2048, 256, 0, stream>>>(xZ2, Wp1, bp1, Wp2, bp2, tprob, N);
}

// Round 4
// 253.463 us; speedup vs baseline: 6.6102x; 1.2629x over previous
//
#include <hip/hip_runtime.h>
#include <math.h>

// ---------------------------------------------------------------------------
// CNE: 2-layer GCN (PyG GCNConv norm w/ self loops) + outcome/propensity heads
// N=100000, E=1600000, IN=128, H=64, T=C=20000.
//
// R4: GEMMs (X@W) moved to MFMA f16 (fp32 accumulate). Per wave: 16x64 output
// tile, W fragments hoisted to VGPRs once per block, A converted fp32->fp16
// in-register. xZ1 stored fp16 so GEMM2 loads A directly as fp16.
// Aggregation stays wave-per-node over binned-CSR (R3 structure).
// ---------------------------------------------------------------------------

#define CHUNK 16384  // edges per binning block
#define BSH 7        // 128 dst nodes per bucket

typedef __attribute__((ext_vector_type(8))) _Float16 half8;
typedef __attribute__((ext_vector_type(4))) float f32x4;

__device__ __forceinline__ float wave_sum64(float v) {
#pragma unroll
  for (int m = 32; m >= 1; m >>= 1) v += __shfl_xor(v, m, 64);
  return v;
}

__device__ __forceinline__ float lrelu(float x) { return x > 0.0f ? x : 0.01f * x; }

// ---- bucket histogram per chunk (LDS only) ----
__global__ void k_count(const int* __restrict__ dst, int E, int nbuck,
                        int* __restrict__ bcount, int* __restrict__ blkcount) {
  __shared__ int bh[1024];
  int t = threadIdx.x;
  for (int i = t; i < nbuck; i += 256) bh[i] = 0;
  __syncthreads();
  int e0 = blockIdx.x * CHUNK;
  int e1 = min(e0 + CHUNK, E);
  for (int e = e0 + t; e < e1; e += 256) atomicAdd(&bh[dst[e] >> BSH], 1);
  __syncthreads();
  for (int i = t; i < nbuck; i += 256) {
    int c = bh[i];
    blkcount[blockIdx.x * nbuck + i] = c;
    if (c) atomicAdd(&bcount[i], c);
  }
}

// ---- exclusive scan of bucket counts (nbuck <= 1024), one block ----
__global__ void k_scan1(const int* __restrict__ bcount, int* __restrict__ bbase, int nbuck) {
  __shared__ int s[1024];
  int t = threadIdx.x;
  int v = (t < nbuck) ? bcount[t] : 0;
  s[t] = v;
  __syncthreads();
  for (int off = 1; off < 1024; off <<= 1) {
    int u = (t >= off) ? s[t - off] : 0;
    __syncthreads();
    s[t] += u;
    __syncthreads();
  }
  if (t < nbuck) bbase[t] = s[t] - v;
}

// ---- per-(block,bucket) offsets: column scan over nblk entries ----
__global__ void k_scan2(const int* __restrict__ blkcount, const int* __restrict__ bbase,
                        int* __restrict__ blkoff, int nblk, int nbuck) {
  int lane = threadIdx.x & 63;
  int b = (blockIdx.x * blockDim.x + threadIdx.x) >> 6;  // one wave per bucket
  if (b >= nbuck) return;
  int carry = bbase[b];
  for (int base = 0; base < nblk; base += 64) {
    int i = base + lane;
    int v = (i < nblk) ? blkcount[i * nbuck + b] : 0;
    int x = v;
#pragma unroll
    for (int off = 1; off < 64; off <<= 1) {
      int u = __shfl_up(x, off, 64);
      if (lane >= off) x += u;
    }
    if (i < nblk) blkoff[i * nbuck + b] = carry + (x - v);
    carry += __shfl(x, 63, 64);
  }
}

// ---- binned scatter: pack src (bits 0..19) | (dst & 127) << 20 ----
__global__ void k_bscatter(const int* __restrict__ src, const int* __restrict__ dst,
                           int E, int nbuck, const int* __restrict__ blkoff,
                           unsigned int* __restrict__ pairs) {
  __shared__ int cur[1024];
  int t = threadIdx.x;
  for (int i = t; i < nbuck; i += 256) cur[i] = blkoff[blockIdx.x * nbuck + i];
  __syncthreads();
  int e0 = blockIdx.x * CHUNK;
  int e1 = min(e0 + CHUNK, E);
  for (int e = e0 + t; e < e1; e += 256) {
    int s = src[e];
    int d = dst[e];
    int p = atomicAdd(&cur[d >> BSH], 1);
    pairs[p] = (unsigned int)s | ((unsigned int)(d & 127) << 20);
  }
}

// ---- in-bucket sort -> per-node CSR + degree + dinv ----
__global__ void k_sort(const unsigned int* __restrict__ pairs, const int* __restrict__ bbase,
                       const int* __restrict__ bcount, int* __restrict__ slot,
                       int* __restrict__ offs, int* __restrict__ cntout,
                       float* __restrict__ dinv, int N) {
  __shared__ int hist[128];
  __shared__ int loc[128];
  __shared__ int cur[128];
  int b = blockIdx.x, t = threadIdx.x;
  if (t < 128) hist[t] = 0;
  __syncthreads();
  int start = bbase[b], cnt = bcount[b];
  for (int i = t; i < cnt; i += 256) atomicAdd(&hist[pairs[start + i] >> 20], 1);
  __syncthreads();
  if (t < 128) loc[t] = hist[t];
  __syncthreads();
  for (int off = 1; off < 128; off <<= 1) {
    int u = (t >= off && t < 128) ? loc[t - off] : 0;
    __syncthreads();
    if (t < 128) loc[t] += u;
    __syncthreads();
  }
  if (t < 128) {
    int ex = loc[t] - hist[t];  // exclusive scan
    cur[t] = ex;
    int node = (b << BSH) + t;
    if (node < N) {
      offs[node] = start + ex;
      cntout[node] = hist[t];
      dinv[node] = rsqrtf((float)(hist[t] + 1));
    }
  }
  __syncthreads();
  for (int i = t; i < cnt; i += 256) {
    unsigned int p = pairs[start + i];
    int d = (int)(p >> 20);
    int pos = atomicAdd(&cur[d], 1);
    slot[start + pos] = (int)(p & 0xFFFFFu);
  }
}

// ---- MFMA GEMM: G16 = fp16( dinv * (X @ W) ), X:[N,K] (TIN), W:[K,64] f32 ----
// wave computes 16 rows x 64 cols; block = 4 waves = 64 rows.
// A frag: row=lane&15, k=(lane>>4)*8+j ; B frag: col=lane&15, same k map;
// D: col=lane&15, row=(lane>>4)*4+reg  (m89-verified mapping).
template <int K, typename TIN>
__launch_bounds__(256)
__global__ void k_gemm_mfma(const TIN* __restrict__ X, const float* __restrict__ W,
                            const float* __restrict__ dinv, _Float16* __restrict__ G, int N) {
  constexpr int KST = K / 32;
  int lane = threadIdx.x & 63;
  int wv = threadIdx.x >> 6;
  int lo = lane & 15;   // A row / B,D col (within tile)
  int hi = lane >> 4;   // k-group for A/B; row-group for D

  // hoist B (W) fragments: bfrag[ks][ct][j] = W[ks*32 + hi*8 + j][ct*16 + lo]
  half8 bfrag[KST][4];
#pragma unroll
  for (int ks = 0; ks < KST; ks++)
#pragma unroll
    for (int ct = 0; ct < 4; ct++)
#pragma unroll
      for (int j = 0; j < 8; j++)
        bfrag[ks][ct][j] = (_Float16)W[(ks * 32 + hi * 8 + j) * 64 + ct * 16 + lo];

  int r0 = (blockIdx.x * 4 + wv) * 16;
  if (r0 >= N) return;

  f32x4 acc[4];
#pragma unroll
  for (int ct = 0; ct < 4; ct++)
#pragma unroll
    for (int j = 0; j < 4; j++) acc[ct][j] = 0.0f;

  int ar = min(r0 + lo, N - 1);
#pragma unroll
  for (int ks = 0; ks < KST; ks++) {
    const TIN* ap = X + (size_t)ar * K + ks * 32 + hi * 8;
    half8 a;
    if constexpr (sizeof(TIN) == 4) {
      const float4* p = (const float4*)ap;
      float4 u = p[0], v = p[1];
      a[0] = (_Float16)u.x; a[1] = (_Float16)u.y; a[2] = (_Float16)u.z; a[3] = (_Float16)u.w;
      a[4] = (_Float16)v.x; a[5] = (_Float16)v.y; a[6] = (_Float16)v.z; a[7] = (_Float16)v.w;
    } else {
      a = *(const half8*)ap;
    }
#pragma unroll
    for (int ct = 0; ct < 4; ct++)
      acc[ct] = __builtin_amdgcn_mfma_f32_16x16x32_f16(a, bfrag[ks][ct], acc[ct], 0, 0, 0);
  }

  // epilogue: D row = hi*4 + j, col = ct*16 + lo; scale by dinv[row]
  float dv[4];
#pragma unroll
  for (int j = 0; j < 4; j++) dv[j] = dinv[min(r0 + hi * 4 + j, N - 1)];
#pragma unroll
  for (int j = 0; j < 4; j++) {
    int rr = r0 + hi * 4 + j;
    if (rr < N) {
#pragma unroll
      for (int ct = 0; ct < 4; ct++)
        G[(size_t)rr * 64 + ct * 16 + lo] = (_Float16)(acc[ct][j] * dv[j]);
    }
  }
}

// ---- aggregation: wave per node; Out[i]=act(b + dinv[i]*(G[i]+sum G[src])) ----
template <typename TOUT>
__global__ void k_agg(const _Float16* __restrict__ G, const int* __restrict__ offs,
                      const int* __restrict__ count, const int* __restrict__ slot,
                      const float* __restrict__ dinv, const float* __restrict__ bias,
                      TOUT* __restrict__ Out, int N, int do_relu) {
  int lane = threadIdx.x & 63;
  int wid = (blockIdx.x * blockDim.x + threadIdx.x) >> 6;
  if (wid >= N) return;
  int r = __builtin_amdgcn_readfirstlane(wid);
  int start = offs[r], cnt = count[r];
  float acc0 = (float)G[(size_t)r * 64 + lane];
  float acc1 = 0.f, acc2 = 0.f, acc3 = 0.f;
  int j = 0;
  for (; j + 8 <= cnt; j += 8) {
    int s[8];
#pragma unroll
    for (int u = 0; u < 8; u++) s[u] = slot[start + j + u];
    float v[8];
#pragma unroll
    for (int u = 0; u < 8; u++) v[u] = (float)G[(size_t)s[u] * 64 + lane];
    acc0 += v[0] + v[4];
    acc1 += v[1] + v[5];
    acc2 += v[2] + v[6];
    acc3 += v[3] + v[7];
  }
  for (; j < cnt; j++) {
    int s = slot[start + j];
    acc0 += (float)G[(size_t)s * 64 + lane];
  }
  float val = bias[lane] + dinv[r] * (acc0 + acc1 + acc2 + acc3);
  if (do_relu) val = fmaxf(val, 0.f);
  Out[(size_t)r * 64 + lane] = (TOUT)val;
}

// ---- outcome heads ----
__global__ void k_heads(const float* __restrict__ Z, const int* __restrict__ treat,
                        const int* __restrict__ ctrl, int T, int C,
                        const float* __restrict__ Wy1, const float* __restrict__ by1,
                        const float* __restrict__ Wy0, const float* __restrict__ by0,
                        float* __restrict__ y1, float* __restrict__ yc0,
                        float* __restrict__ y0, float* __restrict__ yc1) {
  int lane = threadIdx.x & 63;
  int wid = (blockIdx.x * blockDim.x + threadIdx.x) >> 6;
  if (wid >= T + C) return;
  bool treated = wid < T;
  int idx = treated ? wid : wid - T;
  int row = treated ? treat[idx] : ctrl[idx];
  row = __builtin_amdgcn_readfirstlane(row);
  float v = Z[(size_t)row * 64 + lane];
  float s1 = wave_sum64(v * Wy1[lane]);
  float s0 = wave_sum64(v * Wy0[lane]);
  if (lane == 0) {
    float a1 = lrelu(s1 + by1[0]);
    float a0 = lrelu(s0 + by0[0]);
    if (treated) { y1[idx] = a1; yc0[idx] = a0; }
    else         { yc1[idx] = a1; y0[idx] = a0; }
  }
}

// ---- propensity head ----
__launch_bounds__(256)
__global__ void k_tprob(const float* __restrict__ Z, const float* __restrict__ Wp1,
                        const float* __restrict__ bp1, const float* __restrict__ Wp2,
                        const float* __restrict__ bp2, float* __restrict__ tprob, int N) {
  int lane = threadIdx.x & 63;
  float w[64];
#pragma unroll
  for (int k = 0; k < 64; k++) w[k] = Wp1[k * 64 + lane];
  float wp2a = Wp2[lane * 2 + 0], wp2b = Wp2[lane * 2 + 1];
  float b1l = bp1[lane];
  float b20 = bp2[0], b21 = bp2[1];
  int wid = (blockIdx.x * blockDim.x + threadIdx.x) >> 6;
  int nwave = (gridDim.x * blockDim.x) >> 6;
  for (int row = wid; row < N; row += nwave) {
    int r = __builtin_amdgcn_readfirstlane(row);
    const float4* zr = (const float4*)(Z + (size_t)r * 64);
    float a0 = 0.f, a1 = 0.f, a2 = 0.f, a3 = 0.f;
#pragma unroll
    for (int k = 0; k < 16; k++) {
      float4 xv = zr[k];
      a0 = fmaf(xv.x, w[4 * k + 0], a0);
      a1 = fmaf(xv.y, w[4 * k + 1], a1);
      a2 = fmaf(xv.z, w[4 * k + 2], a2);
      a3 = fmaf(xv.w, w[4 * k + 3], a3);
    }
    float hp = lrelu(b1l + a0 + a1 + a2 + a3);
    float s0 = wave_sum64(hp * wp2a);
    float s1 = wave_sum64(hp * wp2b);
    if (lane == 0) {
      tprob[(size_t)r * 2 + 0] = lrelu(s0 + b20);
      tprob[(size_t)r * 2 + 1] = lrelu(s1 + b21);
    }
  }
}

extern "C" void kernel_launch(void* const* d_in, const int* in_sizes, int n_in,
                              void* d_out, int out_size, void* d_ws, size_t ws_size,
                              hipStream_t stream) {
  const int IN = 128, H = 64;
  const int N = in_sizes[0] / IN;
  const int E = in_sizes[1] / 2;
  const int T = in_sizes[2];
  const int C = in_sizes[3];
  const int nbuck = (N + 127) >> BSH;         // 782
  const int nblk = (E + CHUNK - 1) / CHUNK;   // 98

  const float* x    = (const float*)d_in[0];
  const int*   ei   = (const int*)d_in[1];
  const int*   src  = ei;
  const int*   dst  = ei + E;
  const int*   trt  = (const int*)d_in[2];
  const int*   ctl  = (const int*)d_in[3];
  const float* W1   = (const float*)d_in[4];
  const float* b1   = (const float*)d_in[5];
  const float* W2   = (const float*)d_in[6];
  const float* b2   = (const float*)d_in[7];
  const float* Wy1  = (const float*)d_in[8];
  const float* by1  = (const float*)d_in[9];
  const float* Wy0  = (const float*)d_in[10];
  const float* by0  = (const float*)d_in[11];
  const float* Wp1  = (const float*)d_in[12];
  const float* bp1  = (const float*)d_in[13];
  const float* Wp2  = (const float*)d_in[14];
  const float* bp2  = (const float*)d_in[15];

  float* out   = (float*)d_out;
  float* y1    = out;                          // [T]
  float* yc0   = out + T;                      // [T]
  float* y0    = out + 2 * T;                  // [C]
  float* yc1   = out + 2 * T + C;              // [C]
  float* tprob = out + 2 * T + 2 * C;          // [N,2]
  float* xZ2   = out + 2 * T + 2 * C + 2 * N;  // [N,64]

  // workspace layout (4-byte units)
  int* bcount    = (int*)d_ws;                      // 1024 (zeroed)
  int* bbase     = bcount + 1024;                   // 1024
  int* blkcount  = bbase + 1024;                    // nblk*nbuck
  int* blkoff    = blkcount + (size_t)nblk * nbuck; // nblk*nbuck
  unsigned int* pairs = (unsigned int*)(blkoff + (size_t)nblk * nbuck);  // E
  int* slot      = (int*)(pairs + E);               // E
  int* offs      = slot + E;                        // N
  int* cnt       = offs + N;                        // N
  float* dinv    = (float*)(cnt + N);               // N
  // align g16 to 16B
  size_t goff = ((size_t)(dinv + N - (float*)d_ws) + 3) & ~(size_t)3;
  _Float16* g16 = (_Float16*)((float*)d_ws + goff);     // N*64 halves
  _Float16* xZ1 = g16 + (size_t)N * 64;                 // N*64 halves

  hipMemsetAsync(bcount, 0, sizeof(int) * 1024, stream);

  k_count<<<nblk, 256, 0, stream>>>(dst, E, nbuck, bcount, blkcount);
  k_scan1<<<1, 1024, 0, stream>>>(bcount, bbase, nbuck);
  k_scan2<<<(nbuck * 64 + 255) / 256, 256, 0, stream>>>(blkcount, bbase, blkoff, nblk, nbuck);
  k_bscatter<<<nblk, 256, 0, stream>>>(src, dst, E, nbuck, blkoff, pairs);
  k_sort<<<nbuck, 256, 0, stream>>>(pairs, bbase, bcount, slot, offs, cnt, dinv, N);

  const int ngemm = (N + 63) / 64;

  // layer 1: g16 = fp16(dinv*(x@W1)); xZ1(fp16) = relu(b1 + dinv*(g_self+sum))
  k_gemm_mfma<128, float><<<ngemm, 256, 0, stream>>>(x, W1, dinv, g16, N);
  k_agg<_Float16><<<((size_t)N * 64 + 255) / 256, 256, 0, stream>>>(
      g16, offs, cnt, slot, dinv, b1, xZ1, N, 1);

  // layer 2: g16 = fp16(dinv*(xZ1@W2)); xZ2(fp32) = b2 + dinv*(g_self+sum)
  k_gemm_mfma<64, _Float16><<<ngemm, 256, 0, stream>>>(xZ1, W2, dinv, g16, N);
  k_agg<float><<<((size_t)N * 64 + 255) / 256, 256, 0, stream>>>(
      g16, offs, cnt, slot, dinv, b2, xZ2, N, 0);

  // heads
  k_heads<<<((size_t)(T + C) * 64 + 255) / 256, 256, 0, stream>>>(
      xZ2, trt, ctl, T, C, Wy1, by1, Wy0, by0, y1, yc0, y0, yc1);
  k_tprob<<<2048, 256, 0, stream>>>(xZ2, Wp1, bp1, Wp2, bp2, tprob, N);
}